// Round 1
// baseline (713.952 us; speedup 1.0000x reference)
//
#include <hip/hip_runtime.h>
#include <hip/hip_bf16.h>

typedef unsigned short u16;
typedef unsigned int u32;
typedef __attribute__((ext_vector_type(8))) short short8;
typedef __attribute__((ext_vector_type(4))) float floatx4;

#define MFMA16(a,b,c) __builtin_amdgcn_mfma_f32_16x16x32_bf16((a),(b),(c),0,0,0)

__device__ __forceinline__ u16 f2bf(float f){
  u32 x = __float_as_uint(f);
  x += 0x7FFFu + ((x >> 16) & 1u);
  return (u16)(x >> 16);
}
__device__ __forceinline__ float bf2f(u16 u){
  return __uint_as_float(((u32)u) << 16);
}

// ---------------- weight transpose+convert: wt[j][d] = bf16(w[d][j]) -------------
__global__ __launch_bounds__(256) void k_wt(const float* __restrict__ w, u16* __restrict__ wt){
  int idx = blockIdx.x * 256 + threadIdx.x;   // 0..262143
  int j = idx >> 9, d = idx & 511;
  wt[idx] = f2bf(w[d * 512 + j]);
}

// ---------------- 5-way projection GEMM: y = x @ w + b, bf16 MFMA ----------------
// z: 0=Q(wq),1=K(wk),2=V(wv, transposed out),3=Q1(wq1),4=K1(wk1)
__global__ __launch_bounds__(256) void k_proj(
    const float* __restrict__ xq, const float* __restrict__ xk, const float* __restrict__ xv,
    const u16* __restrict__ wts,
    const float* __restrict__ bq, const float* __restrict__ bk, const float* __restrict__ bv,
    const float* __restrict__ bq1, const float* __restrict__ bk1,
    u16* __restrict__ Qh, u16* __restrict__ Kh, u16* __restrict__ Vt,
    u16* __restrict__ Q1h, u16* __restrict__ K1h)
{
  __shared__ __align__(16) u16 Xs[64][72];
  __shared__ __align__(16) u16 Wsh[64][72];
  int z = blockIdx.z;
  const float* x; const float* bias; u16* out; int vtm = 0;
  switch (z){
    case 0: x = xq; bias = bq;  out = Qh;  break;
    case 1: x = xk; bias = bk;  out = Kh;  break;
    case 2: x = xv; bias = bv;  out = Vt;  vtm = 1; break;
    case 3: x = xq; bias = bq1; out = Q1h; break;
    default: x = xk; bias = bk1; out = K1h; break;
  }
  const u16* wt = wts + (size_t)z * 262144;
  int tid = threadIdx.x, lane = tid & 63, wid = tid >> 6;
  int wm = wid >> 1, wn = wid & 1;
  int m0 = blockIdx.x * 64, n0 = blockIdx.y * 64;
  int srow = tid >> 2, sc = (tid & 3) * 16;
  int arow = lane & 15, kg = lane >> 4;

  floatx4 acc[2][2];
  #pragma unroll
  for (int i = 0; i < 2; ++i)
    #pragma unroll
    for (int j = 0; j < 2; ++j)
      acc[i][j] = (floatx4){0.f, 0.f, 0.f, 0.f};

  for (int k0 = 0; k0 < 512; k0 += 64){
    const float4* xp = (const float4*)(x + (size_t)(m0 + srow) * 512 + k0 + sc);
    float4 f0 = xp[0], f1 = xp[1], f2 = xp[2], f3 = xp[3];
    short8 v0, v1;
    v0[0] = (short)f2bf(f0.x); v0[1] = (short)f2bf(f0.y); v0[2] = (short)f2bf(f0.z); v0[3] = (short)f2bf(f0.w);
    v0[4] = (short)f2bf(f1.x); v0[5] = (short)f2bf(f1.y); v0[6] = (short)f2bf(f1.z); v0[7] = (short)f2bf(f1.w);
    v1[0] = (short)f2bf(f2.x); v1[1] = (short)f2bf(f2.y); v1[2] = (short)f2bf(f2.z); v1[3] = (short)f2bf(f2.w);
    v1[4] = (short)f2bf(f3.x); v1[5] = (short)f2bf(f3.y); v1[6] = (short)f2bf(f3.z); v1[7] = (short)f2bf(f3.w);
    *(short8*)&Xs[srow][sc]     = v0;
    *(short8*)&Xs[srow][sc + 8] = v1;
    const u16* wp = wt + (size_t)(n0 + srow) * 512 + k0 + sc;
    *(short8*)&Wsh[srow][sc]     = *(const short8*)wp;
    *(short8*)&Wsh[srow][sc + 8] = *(const short8*)(wp + 8);
    __syncthreads();
    #pragma unroll
    for (int kk = 0; kk < 2; ++kk){
      short8 a0 = *(const short8*)&Xs[wm * 32 + arow][kk * 32 + kg * 8];
      short8 a1 = *(const short8*)&Xs[wm * 32 + 16 + arow][kk * 32 + kg * 8];
      short8 b0 = *(const short8*)&Wsh[wn * 32 + arow][kk * 32 + kg * 8];
      short8 b1 = *(const short8*)&Wsh[wn * 32 + 16 + arow][kk * 32 + kg * 8];
      acc[0][0] = MFMA16(a0, b0, acc[0][0]);
      acc[0][1] = MFMA16(a0, b1, acc[0][1]);
      acc[1][0] = MFMA16(a1, b0, acc[1][0]);
      acc[1][1] = MFMA16(a1, b1, acc[1][1]);
    }
    __syncthreads();
  }
  #pragma unroll
  for (int mm = 0; mm < 2; ++mm)
    #pragma unroll
    for (int nn = 0; nn < 2; ++nn){
      int j = n0 + wn * 32 + nn * 16 + arow;
      int h = j >> 6, dh = j & 63;
      float bval = bias[j];
      #pragma unroll
      for (int i = 0; i < 4; ++i){
        int sg = m0 + wm * 32 + mm * 16 + kg * 4 + i;
        int bb = sg >> 10, s = sg & 1023;
        float val = acc[mm][nn][i] + bval;
        size_t o = vtm ? (((size_t)((bb << 3) + h) * 64 + dh) * 1024 + s)
                       : (((size_t)((bb << 3) + h) * 1024 + s) * 64 + dh);
        out[o] = f2bf(val);
      }
    }
}

// ---------------- fused dual-QK attention + r_att + PV ----------------
__global__ __launch_bounds__(256, 2) void k_attn(
    const u16* __restrict__ Qh, const u16* __restrict__ Kh, const u16* __restrict__ Vt,
    const u16* __restrict__ Q1h, const u16* __restrict__ K1h,
    const int* __restrict__ mask, u16* __restrict__ xa, float* __restrict__ ratt)
{
  __shared__ __align__(16) u16 es[16 * 1024];  // energy logits (bf16), then p
  __shared__ __align__(16) u16 gs[16 * 1024];  // gate (bf16), then attention; XOR-swizzled
  int tid = threadIdx.x, lane = tid & 63, wid = tid >> 6;
  int qt = blockIdx.x, b = blockIdx.y;
  int arow = lane & 15, kg = lane >> 4;

  u32 mb = 0;
  #pragma unroll
  for (int i = 0; i < 16; ++i) mb |= (mask[b * 1024 + lane + i * 64] != 0 ? 1u : 0u) << i;

  float racc[64];
  #pragma unroll
  for (int i = 0; i < 64; ++i) racc[i] = 0.f;

  for (int h = 0; h < 8; ++h){
    size_t hb = (size_t)(b * 8 + h);
    const u16* qp  = Qh  + (hb * 1024 + qt * 16 + arow) * 64 + kg * 8;
    const u16* q1p = Q1h + (hb * 1024 + qt * 16 + arow) * 64 + kg * 8;
    short8 aq0 = *(const short8*)qp,  aq1 = *(const short8*)(qp + 32);
    short8 ap0 = *(const short8*)q1p, ap1 = *(const short8*)(q1p + 32);

    // pass1: sample logits -> sigmoid gate -> gs
    #pragma unroll 4
    for (int t = 0; t < 16; ++t){
      int kcol = wid * 256 + t * 16 + arow;
      const u16* kp = K1h + (hb * 1024 + kcol) * 64 + kg * 8;
      floatx4 c = (floatx4){0.f, 0.f, 0.f, 0.f};
      c = MFMA16(ap0, *(const short8*)kp, c);
      c = MFMA16(ap1, *(const short8*)(kp + 32), c);
      #pragma unroll
      for (int i = 0; i < 4; ++i){
        int row = kg * 4 + i;
        int col = wid * 256 + t * 16 + arow;
        float gate = 1.0f / (1.0f + __expf(-c[i] * 0.125f));
        gs[(row * 1024 + col) ^ ((row & 7) << 3)] = f2bf(gate);
      }
    }
    // pass2: energy logits -> es (raw, unscaled)
    #pragma unroll 4
    for (int t = 0; t < 16; ++t){
      int kcol = wid * 256 + t * 16 + arow;
      const u16* kp = Kh + (hb * 1024 + kcol) * 64 + kg * 8;
      floatx4 c = (floatx4){0.f, 0.f, 0.f, 0.f};
      c = MFMA16(aq0, *(const short8*)kp, c);
      c = MFMA16(aq1, *(const short8*)(kp + 32), c);
      #pragma unroll
      for (int i = 0; i < 4; ++i){
        int row = kg * 4 + i;
        int col = wid * 256 + t * 16 + arow;
        es[row * 1024 + col] = f2bf(c[i]);
      }
    }
    __syncthreads();
    // pass3+4: per-row softmax (f32) + gate + r_att accumulate; wave owns rows wid*4..+3
    #pragma unroll
    for (int r = 0; r < 4; ++r){
      int row = wid * 4 + r;
      float ev[16];
      #pragma unroll
      for (int i = 0; i < 16; ++i) ev[i] = bf2f(es[row * 1024 + lane + i * 64]);
      float m = -3.0e38f;
      #pragma unroll
      for (int i = 0; i < 16; ++i) if ((mb >> i) & 1u) m = fmaxf(m, ev[i]);
      #pragma unroll
      for (int off = 32; off >= 1; off >>= 1) m = fmaxf(m, __shfl_xor(m, off, 64));
      float p[16]; float sum = 0.f;
      #pragma unroll
      for (int i = 0; i < 16; ++i){
        p[i] = ((mb >> i) & 1u) ? __expf((ev[i] - m) * 0.125f) : 0.f;
        sum += p[i];
      }
      #pragma unroll
      for (int off = 32; off >= 1; off >>= 1) sum += __shfl_xor(sum, off, 64);
      float rl = 1.0f / sum;
      #pragma unroll
      for (int i = 0; i < 16; ++i){
        int col = lane + i * 64;
        int gi = (row * 1024 + col) ^ ((row & 7) << 3);
        float a = p[i] * rl * bf2f(gs[gi]);
        racc[r * 16 + i] += a * 0.125f;
        gs[gi] = f2bf(a);
      }
    }
    __syncthreads();
    // pass5: PV — wave wid owns output cols wid*16..+15 of Dh=64
    floatx4 c0 = (floatx4){0.f, 0.f, 0.f, 0.f}, c1 = (floatx4){0.f, 0.f, 0.f, 0.f};
    int n = wid * 16 + arow;
    const u16* vp = Vt + (hb * 64 + n) * 1024 + kg * 8;
    #pragma unroll 8
    for (int kt = 0; kt < 32; ++kt){
      int k0 = kt * 32 + kg * 8;
      short8 av = *(const short8*)&gs[(arow * 1024 + k0) ^ ((arow & 7) << 3)];
      short8 bv = *(const short8*)(vp + kt * 32);
      if (kt & 1) c1 = MFMA16(av, bv, c1); else c0 = MFMA16(av, bv, c0);
    }
    #pragma unroll
    for (int i = 0; i < 4; ++i){
      int row = kg * 4 + i;
      float val = c0[i] + c1[i];
      xa[((size_t)(b * 1024 + qt * 16 + row)) * 512 + h * 64 + n] = f2bf(val);
    }
    __syncthreads();
  }
  #pragma unroll
  for (int r = 0; r < 4; ++r){
    int sq = qt * 16 + wid * 4 + r;
    #pragma unroll
    for (int i = 0; i < 16; ++i)
      ratt[((size_t)(b * 1024 + sq)) * 1024 + lane + i * 64] = racc[r * 16 + i];
  }
}

// ---------------- final FC: out = xa @ wfc + bfc (f32 out) ----------------
__global__ __launch_bounds__(256) void k_fc(
    const u16* __restrict__ xa, const u16* __restrict__ wt,
    const float* __restrict__ bias, float* __restrict__ out)
{
  __shared__ __align__(16) u16 Xs[64][72];
  __shared__ __align__(16) u16 Wsh[64][72];
  int tid = threadIdx.x, lane = tid & 63, wid = tid >> 6;
  int wm = wid >> 1, wn = wid & 1;
  int m0 = blockIdx.x * 64, n0 = blockIdx.y * 64;
  int srow = tid >> 2, sc = (tid & 3) * 16;
  int arow = lane & 15, kg = lane >> 4;

  floatx4 acc[2][2];
  #pragma unroll
  for (int i = 0; i < 2; ++i)
    #pragma unroll
    for (int j = 0; j < 2; ++j)
      acc[i][j] = (floatx4){0.f, 0.f, 0.f, 0.f};

  for (int k0 = 0; k0 < 512; k0 += 64){
    const u16* xp = xa + (size_t)(m0 + srow) * 512 + k0 + sc;
    *(short8*)&Xs[srow][sc]     = *(const short8*)xp;
    *(short8*)&Xs[srow][sc + 8] = *(const short8*)(xp + 8);
    const u16* wp = wt + (size_t)(n0 + srow) * 512 + k0 + sc;
    *(short8*)&Wsh[srow][sc]     = *(const short8*)wp;
    *(short8*)&Wsh[srow][sc + 8] = *(const short8*)(wp + 8);
    __syncthreads();
    #pragma unroll
    for (int kk = 0; kk < 2; ++kk){
      short8 a0 = *(const short8*)&Xs[wm * 32 + arow][kk * 32 + kg * 8];
      short8 a1 = *(const short8*)&Xs[wm * 32 + 16 + arow][kk * 32 + kg * 8];
      short8 b0 = *(const short8*)&Wsh[wn * 32 + arow][kk * 32 + kg * 8];
      short8 b1 = *(const short8*)&Wsh[wn * 32 + 16 + arow][kk * 32 + kg * 8];
      acc[0][0] = MFMA16(a0, b0, acc[0][0]);
      acc[0][1] = MFMA16(a0, b1, acc[0][1]);
      acc[1][0] = MFMA16(a1, b0, acc[1][0]);
      acc[1][1] = MFMA16(a1, b1, acc[1][1]);
    }
    __syncthreads();
  }
  #pragma unroll
  for (int mm = 0; mm < 2; ++mm)
    #pragma unroll
    for (int nn = 0; nn < 2; ++nn){
      int j = n0 + wn * 32 + nn * 16 + arow;
      float bval = bias[j];
      #pragma unroll
      for (int i = 0; i < 4; ++i){
        int sg = m0 + wm * 32 + mm * 16 + kg * 4 + i;
        out[(size_t)sg * 512 + j] = acc[mm][nn][i] + bval;
      }
    }
}

extern "C" void kernel_launch(void* const* d_in, const int* in_sizes, int n_in,
                              void* d_out, int out_size, void* d_ws, size_t ws_size,
                              hipStream_t stream)
{
  const float* query = (const float*)d_in[0];
  const float* key   = (const float*)d_in[1];
  const float* value = (const float*)d_in[2];
  const int*   mask  = (const int*)d_in[3];
  const float* wq  = (const float*)d_in[4];  const float* bq  = (const float*)d_in[5];
  const float* wk  = (const float*)d_in[6];  const float* bk  = (const float*)d_in[7];
  const float* wv  = (const float*)d_in[8];  const float* bv  = (const float*)d_in[9];
  const float* wq1 = (const float*)d_in[10]; const float* bq1 = (const float*)d_in[11];
  const float* wk1 = (const float*)d_in[12]; const float* bk1 = (const float*)d_in[13];
  const float* wfc = (const float*)d_in[14]; const float* bfc = (const float*)d_in[15];

  u16* ws  = (u16*)d_ws;
  u16* Qh  = ws;
  u16* Kh  = Qh  + 8388608;
  u16* Vt  = Kh  + 8388608;
  u16* Q1h = Vt  + 8388608;
  u16* K1h = Q1h + 8388608;
  u16* xa  = K1h + 8388608;
  u16* wts = xa  + 8388608;   // 6 * 262144 bf16

  float* outx = (float*)d_out;
  float* ratt = outx + 8388608;

  const float* wsrc[6] = {wq, wk, wv, wq1, wk1, wfc};
  for (int z = 0; z < 6; ++z)
    k_wt<<<dim3(1024), dim3(256), 0, stream>>>(wsrc[z], wts + (size_t)z * 262144);

  k_proj<<<dim3(256, 8, 5), dim3(256), 0, stream>>>(
      query, key, value, wts, bq, bk, bv, bq1, bk1, Qh, Kh, Vt, Q1h, K1h);

  k_attn<<<dim3(64, 16), dim3(256), 0, stream>>>(
      Qh, Kh, Vt, Q1h, K1h, mask, xa, ratt);

  k_fc<<<dim3(256, 8), dim3(256), 0, stream>>>(
      xa, wts + 5 * 262144, bfc, outx);
}